// Round 6
// baseline (112.799 us; speedup 1.0000x reference)
//
#include <hip/hip_runtime.h>
#include <hip/hip_bf16.h>
#include <math.h>

#define N_LOC   8192
#define C_SIZE  2048
#define A_SIZE  512
#define CTRL_IN 1024
#define D_FULL  2560   // A_SIZE + C_SIZE
#define EPS_F   1e-7f
#define NCHUNK  128    // row chunks for read_vec partials (8192/NCHUNK=64 rows/chunk)

typedef float f4 __attribute__((ext_vector_type(4)));

__device__ __forceinline__ f4 nt4(const f4* p) { return __builtin_nontemporal_load(p); }
__device__ __forceinline__ float ntf(const float* p) { return __builtin_nontemporal_load(p); }

__device__ __forceinline__ float waveReduceSum(float v) {
    #pragma unroll
    for (int off = 32; off > 0; off >>= 1) v += __shfl_xor(v, off, 64);
    return v;
}
__device__ __forceinline__ float waveReduceMax(float v) {
    #pragma unroll
    for (int off = 32; off > 0; off >>= 1) v = fmaxf(v, __shfl_xor(v, off, 64));
    return v;
}

// ---------------------------------------------------------------- K1: all mat-vecs, block-per-row
// W streams are single-use -> NONTEMPORAL loads (bypass L3, stream from HBM ~6.3 TB/s;
// L3 hit path measured at only ~3.4 TB/s across R1-R5 variants).
// h/x are tiny and re-read -> normal loads (L2-served).
// blocks [0,6656): h-driven rows (8192-long dot), 256 thr, 8 W-f4 + 8 h-f4 per thread.
// blocks [6656,8704): x-driven rows (1024-long dot).
__global__ __launch_bounds__(256) void k_matvec(
    const float* __restrict__ h, const float* __restrict__ x,
    const float* __restrict__ Wq, const float* __restrict__ bq,
    const float* __restrict__ We, const float* __restrict__ be,
    const float* __restrict__ Wch, const float* __restrict__ Wci,
    float* __restrict__ q_out, float* __restrict__ erase_out,
    float* __restrict__ wh_out, float* __restrict__ wx_out)
{
    __shared__ float red[4];
    int tid  = threadIdx.x;
    int lane = tid & 63;
    int wid  = tid >> 6;
    int blk  = blockIdx.x;

    float acc;
    float bias = 0.f;
    float* out;

    if (blk < 6656) {
        const float* W;
        if (blk < 2560)      { int r = blk;        W = Wq  + (size_t)r * 8192; bias = bq[r]; out = q_out + r; }
        else if (blk < 4608) { int r = blk - 2560; W = We  + (size_t)r * 8192; bias = be[r]; out = erase_out + r; }
        else                 { int r = blk - 4608; W = Wch + (size_t)r * 8192; out = wh_out + r; }

        const f4* W4 = (const f4*)W;
        const f4* h4 = (const f4*)h;
        f4 w[8], v[8];
        #pragma unroll
        for (int u = 0; u < 8; ++u) w[u] = nt4(W4 + tid + 256 * u);
        #pragma unroll
        for (int u = 0; u < 8; ++u) v[u] = h4[tid + 256 * u];
        f4 a4 = w[0] * v[0];
        #pragma unroll
        for (int u = 1; u < 8; ++u) a4 += w[u] * v[u];
        acc = a4.x + a4.y + a4.z + a4.w;
    } else {
        int r = blk - 6656;              // 0..2047
        const f4* W4 = (const f4*)(Wci + (size_t)r * 1024);
        const f4* x4 = (const f4*)x;
        f4 w = nt4(W4 + tid);
        f4 v = x4[tid];
        f4 p = w * v;
        acc = p.x + p.y + p.z + p.w;
        out = wx_out + r;
    }

    acc = waveReduceSum(acc);
    if (lane == 0) red[wid] = acc;
    __syncthreads();
    if (tid == 0) *out = red[0] + red[1] + red[2] + red[3] + bias;
}

// ---------------------------------------------------------------- K2: scalars + cdiff
// scal[0]=beta, scal[1]=gamma, scal[2]=q_norm, scal[3]=alpha
__global__ void k_scalars(const float* __restrict__ h, const float* __restrict__ x,
                          const float* __restrict__ us, const float* __restrict__ bs,
                          const float* __restrict__ ul, const float* __restrict__ bl,
                          const float* __restrict__ uca, const float* __restrict__ bca,
                          const float* __restrict__ q, const float* __restrict__ erase,
                          const float* __restrict__ wh, const float* __restrict__ wx,
                          float* __restrict__ scal, float* __restrict__ cdiff)
{
    __shared__ float red[16];
    __shared__ float sh_alpha;
    int tid = threadIdx.x, lane = tid & 63, wid = tid >> 6;

    float s_us = 0.f, s_ul = 0.f, s_a = 0.f, s_q2 = 0.f;
    for (int i = tid; i < 8192; i += 1024) {
        float hv = h[i];
        s_us += us[i] * hv;
        s_ul += ul[i] * hv;
        s_a  += uca[i] * hv;
    }
    { int i = tid; if (i < 1024) s_a += uca[8192 + i] * x[i]; }
    for (int i = tid; i < 2560; i += 1024) { float qv = q[i]; s_q2 += qv * qv; }

    float vals[4] = { s_us, s_ul, s_a, s_q2 };
    float res[4];
    #pragma unroll
    for (int k = 0; k < 4; ++k) {
        float v = waveReduceSum(vals[k]);
        __syncthreads();
        if (lane == 0) red[wid] = v;
        __syncthreads();
        float r = 0.f;
        if (tid == 0) { for (int i = 0; i < 16; ++i) r += red[i]; }
        res[k] = r;
    }

    if (tid == 0) {
        float z = res[0] + bs[0];
        float sp = (z > 20.f) ? z : log1pf(expf(z));
        float beta  = sp + 1.0f;
        float gamma = 1.f / (1.f + expf(-(res[1] + bl[0])));
        float alpha = res[2] + bca[0];
        float qn    = fmaxf(sqrtf(res[3]), EPS_F);
        scal[0] = beta; scal[1] = gamma; scal[2] = qn; scal[3] = alpha;
        sh_alpha = alpha;
    }
    __syncthreads();
    float alpha = sh_alpha;
    for (int j = tid; j < 2048; j += 1024) {
        float cand = fmaxf(wh[j] + alpha * wx[j], 0.f);
        cdiff[j] = cand - erase[j];
    }
}

// ---------------------------------------------------------------- K3: row pass (dots, norms, logits, new_ema)
// ma/mc single-use in this kernel -> nt loads; q re-read by all waves -> normal (L2).
__global__ void k_rowpass(const float* __restrict__ ma, const float* __restrict__ mc,
                          const float* __restrict__ q, const float* __restrict__ ema,
                          const float* __restrict__ scal,
                          float* __restrict__ logit, float* __restrict__ newema_out)
{
    int wave = (blockIdx.x * blockDim.x + threadIdx.x) >> 6;
    int lane = threadIdx.x & 63;
    if (wave >= N_LOC) return;
    int row = wave;

    const f4* a4 = (const f4*)(ma + (size_t)row * A_SIZE);
    const f4* c4 = (const f4*)(mc + (size_t)row * C_SIZE);
    const f4* q4 = (const f4*)q;

    f4 dv = {0.f, 0.f, 0.f, 0.f}, sv = {0.f, 0.f, 0.f, 0.f};
    #pragma unroll
    for (int i = lane; i < 128; i += 64) {           // address part: 512 floats
        f4 v = nt4(a4 + i), qq = q4[i];
        dv += v * qq;
        sv += v * v;
    }
    #pragma unroll
    for (int i = lane; i < 512; i += 64) {           // contents part: 2048 floats
        f4 v = nt4(c4 + i), qq = q4[128 + i];
        dv += v * qq;
        sv += v * v;
    }
    float dot = dv.x + dv.y + dv.z + dv.w;
    float ssq = sv.x + sv.y + sv.z + sv.w;
    dot = waveReduceSum(dot);
    ssq = waveReduceSum(ssq);
    if (lane == 0) {
        float beta = scal[0], gamma = scal[1], qn = scal[2];
        float mn  = fmaxf(sqrtf(ssq), EPS_F);
        float sim = beta * dot / (mn * qn);
        float e   = ema[row];
        logit[row]      = sim - gamma * e;
        newema_out[row] = 0.1f * e + 0.9f * sim;
    }
}

// ---------------------------------------------------------------- K4: softmax over 8192 logits
__global__ void k_softmax(const float* __restrict__ logit, float* __restrict__ addr_out)
{
    __shared__ float red[16];
    __shared__ float s_max, s_sum;
    int tid = threadIdx.x, lane = tid & 63, wid = tid >> 6;

    float v[8];
    float lmax = -INFINITY;
    #pragma unroll
    for (int k = 0; k < 8; ++k) { v[k] = logit[tid + k * 1024]; lmax = fmaxf(lmax, v[k]); }
    lmax = waveReduceMax(lmax);
    if (lane == 0) red[wid] = lmax;
    __syncthreads();
    if (tid == 0) { float m = red[0]; for (int i = 1; i < 16; ++i) m = fmaxf(m, red[i]); s_max = m; }
    __syncthreads();
    float m = s_max, lsum = 0.f;
    #pragma unroll
    for (int k = 0; k < 8; ++k) { v[k] = expf(v[k] - m); lsum += v[k]; }
    lsum = waveReduceSum(lsum);
    __syncthreads();
    if (lane == 0) red[wid] = lsum;
    __syncthreads();
    if (tid == 0) { float s = 0.f; for (int i = 0; i < 16; ++i) s += red[i]; s_sum = s; }
    __syncthreads();
    float inv = 1.f / s_sum;
    #pragma unroll
    for (int k = 0; k < 8; ++k) addr_out[tid + k * 1024] = v[k] * inv;
}

// ---------------------------------------------------------------- K5: fused column pass (new_mem + read_vec partials)
// ma/mc nt-loaded (single use), newmem nt-stored (single write, don't pollute L3).
// addr/cdiff tiny + reused -> normal loads.
__global__ void k_colpass(const float* __restrict__ ma, const float* __restrict__ mc,
                          const float* __restrict__ addr, const float* __restrict__ cdiff,
                          float* __restrict__ newmem_out, float* __restrict__ rvpart)
{
    int c     = blockIdx.x * 256 + threadIdx.x;   // 0..2559
    int chunk = blockIdx.y;                       // 0..NCHUNK-1
    const int RPC = N_LOC / NCHUNK;               // 64
    int r0 = chunk * RPC, r1 = r0 + RPC;

    float acc = 0.f;
    if (c < A_SIZE) {
        const float* p = ma + c;
        for (int r = r0; r < r1; ++r) {
            float val = ntf(p + (size_t)r * A_SIZE);
            float a = addr[r];
            if (r != N_LOC - 1) acc += a * val;
        }
    } else {
        int cc = c - A_SIZE;
        float cd = cdiff[cc];
        const float* p = mc + cc;
        float* o = newmem_out + cc;
        for (int r = r0; r < r1; ++r) {
            float val = ntf(p + (size_t)r * C_SIZE);
            float a = addr[r];
            if (r != N_LOC - 1) acc += a * val;
            __builtin_nontemporal_store(val + a * cd, o + (size_t)r * C_SIZE);
        }
    }
    rvpart[(size_t)chunk * D_FULL + c] = acc;
}

// ---------------------------------------------------------------- K6: reduce read_vec partials
__global__ void k_rvreduce(const float* __restrict__ rvpart, float* __restrict__ rv_out)
{
    int c = blockIdx.x * 256 + threadIdx.x;
    if (c >= D_FULL) return;
    float s = 0.f;
    for (int k = 0; k < NCHUNK; ++k) s += rvpart[(size_t)k * D_FULL + c];
    rv_out[c] = s;
}

// ---------------------------------------------------------------- launch
extern "C" void kernel_launch(void* const* d_in, const int* in_sizes, int n_in,
                              void* d_out, int out_size, void* d_ws, size_t ws_size,
                              hipStream_t stream)
{
    const float* h   = (const float*)d_in[0];
    const float* x   = (const float*)d_in[1];
    const float* mc  = (const float*)d_in[2];
    const float* ma  = (const float*)d_in[3];
    const float* ema = (const float*)d_in[4];
    const float* Wq  = (const float*)d_in[5];
    const float* bq  = (const float*)d_in[6];
    const float* us  = (const float*)d_in[7];
    const float* bs  = (const float*)d_in[8];
    const float* ul  = (const float*)d_in[9];
    const float* bl  = (const float*)d_in[10];
    const float* We  = (const float*)d_in[11];
    const float* be  = (const float*)d_in[12];
    const float* Wch = (const float*)d_in[13];
    const float* Wci = (const float*)d_in[14];
    const float* uca = (const float*)d_in[15];
    const float* bca = (const float*)d_in[16];

    float* out = (float*)d_out;
    float* rv_out     = out;                              // 2560
    float* newmem_out = out + D_FULL;                     // 8192*2048
    float* addr_out   = newmem_out + (size_t)N_LOC * C_SIZE; // 8192
    float* newema_out = addr_out + N_LOC;                 // 8192

    float* ws = (float*)d_ws;
    float* w_query = ws;            // 2560
    float* w_erase = ws + 2560;     // 2048
    float* w_wh    = ws + 4608;     // 2048
    float* w_wx    = ws + 6656;     // 2048
    float* w_cdiff = ws + 8704;     // 2048
    float* w_scal  = ws + 10752;    // 8
    float* w_logit = ws + 10760;    // 8192
    float* w_rvp   = ws + 18952;    // NCHUNK*2560

    // K1: all mat-vecs, block-per-row (6656 h-rows + 2048 x-rows), nt W-stream
    k_matvec<<<8704, 256, 0, stream>>>(h, x, Wq, bq, We, be, Wch, Wci,
                                       w_query, w_erase, w_wh, w_wx);
    // K2: scalars + cdiff
    k_scalars<<<1, 1024, 0, stream>>>(h, x, us, bs, ul, bl, uca, bca,
                                      w_query, w_erase, w_wh, w_wx, w_scal, w_cdiff);
    // K3: per-row dot/norm -> logit, new_ema (nt ma/mc)
    k_rowpass<<<2048, 256, 0, stream>>>(ma, mc, w_query, ema, w_scal, w_logit, newema_out);
    // K4: softmax -> address
    k_softmax<<<1, 1024, 0, stream>>>(w_logit, addr_out);
    // K5: fused new_mem + read_vec partials (nt ma/mc reads, nt newmem stores)
    dim3 g5(D_FULL / 256, NCHUNK);
    k_colpass<<<g5, 256, 0, stream>>>(ma, mc, addr_out, w_cdiff, newmem_out, w_rvp);
    // K6: reduce read_vec partials
    k_rvreduce<<<10, 256, 0, stream>>>(w_rvp, rv_out);
}

// Round 7
// 98.726 us; speedup vs baseline: 1.1425x; 1.1425x over previous
//
#include <hip/hip_runtime.h>
#include <hip/hip_bf16.h>
#include <math.h>

#define N_LOC   8192
#define C_SIZE  2048
#define A_SIZE  512
#define CTRL_IN 1024
#define D_FULL  2560   // A_SIZE + C_SIZE
#define EPS_F   1e-7f
#define NCHUNK  128    // row chunks for read_vec partials (8192/NCHUNK=64 rows/chunk)

typedef float f4 __attribute__((ext_vector_type(4)));

__device__ __forceinline__ f4 nt4(const f4* p) { return __builtin_nontemporal_load(p); }

__device__ __forceinline__ float waveReduceSum(float v) {
    #pragma unroll
    for (int off = 32; off > 0; off >>= 1) v += __shfl_xor(v, off, 64);
    return v;
}
__device__ __forceinline__ float waveReduceMax(float v) {
    #pragma unroll
    for (int off = 32; off > 0; off >>= 1) v = fmaxf(v, __shfl_xor(v, off, 64));
    return v;
}

// ---------------------------------------------------------------- K1: all mat-vecs, block-per-row
// W streams are single-use -> NONTEMPORAL loads (bypass L3 allocate path; R6 measured
// matvec 82 -> <49 us from this alone). h/x tiny + re-read -> normal loads (L2).
// ma/mc/newmem are NOT nt anywhere: ma/mc are read twice (rowpass+colpass) and L3
// serves that reuse (R6 measured +33 us when nt broke it).
// blocks [0,6656): h-driven rows (8192-long dot), 256 thr, 8 W-f4 + 8 h-f4 per thread.
// blocks [6656,8704): x-driven rows (1024-long dot).
__global__ __launch_bounds__(256) void k_matvec(
    const float* __restrict__ h, const float* __restrict__ x,
    const float* __restrict__ Wq, const float* __restrict__ bq,
    const float* __restrict__ We, const float* __restrict__ be,
    const float* __restrict__ Wch, const float* __restrict__ Wci,
    float* __restrict__ q_out, float* __restrict__ erase_out,
    float* __restrict__ wh_out, float* __restrict__ wx_out)
{
    __shared__ float red[4];
    int tid  = threadIdx.x;
    int lane = tid & 63;
    int wid  = tid >> 6;
    int blk  = blockIdx.x;

    float acc;
    float bias = 0.f;
    float* out;

    if (blk < 6656) {
        const float* W;
        if (blk < 2560)      { int r = blk;        W = Wq  + (size_t)r * 8192; bias = bq[r]; out = q_out + r; }
        else if (blk < 4608) { int r = blk - 2560; W = We  + (size_t)r * 8192; bias = be[r]; out = erase_out + r; }
        else                 { int r = blk - 4608; W = Wch + (size_t)r * 8192; out = wh_out + r; }

        const f4* W4 = (const f4*)W;
        const f4* h4 = (const f4*)h;
        f4 w[8], v[8];
        #pragma unroll
        for (int u = 0; u < 8; ++u) w[u] = nt4(W4 + tid + 256 * u);
        #pragma unroll
        for (int u = 0; u < 8; ++u) v[u] = h4[tid + 256 * u];
        f4 a4 = w[0] * v[0];
        #pragma unroll
        for (int u = 1; u < 8; ++u) a4 += w[u] * v[u];
        acc = a4.x + a4.y + a4.z + a4.w;
    } else {
        int r = blk - 6656;              // 0..2047
        const f4* W4 = (const f4*)(Wci + (size_t)r * 1024);
        const f4* x4 = (const f4*)x;
        f4 w = nt4(W4 + tid);
        f4 v = x4[tid];
        f4 p = w * v;
        acc = p.x + p.y + p.z + p.w;
        out = wx_out + r;
    }

    acc = waveReduceSum(acc);
    if (lane == 0) red[wid] = acc;
    __syncthreads();
    if (tid == 0) *out = red[0] + red[1] + red[2] + red[3] + bias;
}

// ---------------------------------------------------------------- K2: scalars + cdiff
// scal[0]=beta, scal[1]=gamma, scal[2]=q_norm, scal[3]=alpha
__global__ void k_scalars(const float* __restrict__ h, const float* __restrict__ x,
                          const float* __restrict__ us, const float* __restrict__ bs,
                          const float* __restrict__ ul, const float* __restrict__ bl,
                          const float* __restrict__ uca, const float* __restrict__ bca,
                          const float* __restrict__ q, const float* __restrict__ erase,
                          const float* __restrict__ wh, const float* __restrict__ wx,
                          float* __restrict__ scal, float* __restrict__ cdiff)
{
    __shared__ float red[16];
    __shared__ float sh_alpha;
    int tid = threadIdx.x, lane = tid & 63, wid = tid >> 6;

    float s_us = 0.f, s_ul = 0.f, s_a = 0.f, s_q2 = 0.f;
    for (int i = tid; i < 8192; i += 1024) {
        float hv = h[i];
        s_us += us[i] * hv;
        s_ul += ul[i] * hv;
        s_a  += uca[i] * hv;
    }
    { int i = tid; if (i < 1024) s_a += uca[8192 + i] * x[i]; }
    for (int i = tid; i < 2560; i += 1024) { float qv = q[i]; s_q2 += qv * qv; }

    float vals[4] = { s_us, s_ul, s_a, s_q2 };
    float res[4];
    #pragma unroll
    for (int k = 0; k < 4; ++k) {
        float v = waveReduceSum(vals[k]);
        __syncthreads();
        if (lane == 0) red[wid] = v;
        __syncthreads();
        float r = 0.f;
        if (tid == 0) { for (int i = 0; i < 16; ++i) r += red[i]; }
        res[k] = r;
    }

    if (tid == 0) {
        float z = res[0] + bs[0];
        float sp = (z > 20.f) ? z : log1pf(expf(z));
        float beta  = sp + 1.0f;
        float gamma = 1.f / (1.f + expf(-(res[1] + bl[0])));
        float alpha = res[2] + bca[0];
        float qn    = fmaxf(sqrtf(res[3]), EPS_F);
        scal[0] = beta; scal[1] = gamma; scal[2] = qn; scal[3] = alpha;
        sh_alpha = alpha;
    }
    __syncthreads();
    float alpha = sh_alpha;
    for (int j = tid; j < 2048; j += 1024) {
        float cand = fmaxf(wh[j] + alpha * wx[j], 0.f);
        cdiff[j] = cand - erase[j];
    }
}

// ---------------------------------------------------------------- K3: row pass (dots, norms, logits, new_ema)
// Normal loads: this fetch allocates ma/mc into L3 so K5 hits it.
__global__ void k_rowpass(const float* __restrict__ ma, const float* __restrict__ mc,
                          const float* __restrict__ q, const float* __restrict__ ema,
                          const float* __restrict__ scal,
                          float* __restrict__ logit, float* __restrict__ newema_out)
{
    int wave = (blockIdx.x * blockDim.x + threadIdx.x) >> 6;
    int lane = threadIdx.x & 63;
    if (wave >= N_LOC) return;
    int row = wave;

    const f4* a4 = (const f4*)(ma + (size_t)row * A_SIZE);
    const f4* c4 = (const f4*)(mc + (size_t)row * C_SIZE);
    const f4* q4 = (const f4*)q;

    f4 dv = {0.f, 0.f, 0.f, 0.f}, sv = {0.f, 0.f, 0.f, 0.f};
    #pragma unroll
    for (int i = lane; i < 128; i += 64) {           // address part: 512 floats
        f4 v = a4[i], qq = q4[i];
        dv += v * qq;
        sv += v * v;
    }
    #pragma unroll
    for (int i = lane; i < 512; i += 64) {           // contents part: 2048 floats
        f4 v = c4[i], qq = q4[128 + i];
        dv += v * qq;
        sv += v * v;
    }
    float dot = dv.x + dv.y + dv.z + dv.w;
    float ssq = sv.x + sv.y + sv.z + sv.w;
    dot = waveReduceSum(dot);
    ssq = waveReduceSum(ssq);
    if (lane == 0) {
        float beta = scal[0], gamma = scal[1], qn = scal[2];
        float mn  = fmaxf(sqrtf(ssq), EPS_F);
        float sim = beta * dot / (mn * qn);
        float e   = ema[row];
        logit[row]      = sim - gamma * e;
        newema_out[row] = 0.1f * e + 0.9f * sim;
    }
}

// ---------------------------------------------------------------- K4: softmax over 8192 logits
__global__ void k_softmax(const float* __restrict__ logit, float* __restrict__ addr_out)
{
    __shared__ float red[16];
    __shared__ float s_max, s_sum;
    int tid = threadIdx.x, lane = tid & 63, wid = tid >> 6;

    float v[8];
    float lmax = -INFINITY;
    #pragma unroll
    for (int k = 0; k < 8; ++k) { v[k] = logit[tid + k * 1024]; lmax = fmaxf(lmax, v[k]); }
    lmax = waveReduceMax(lmax);
    if (lane == 0) red[wid] = lmax;
    __syncthreads();
    if (tid == 0) { float m = red[0]; for (int i = 1; i < 16; ++i) m = fmaxf(m, red[i]); s_max = m; }
    __syncthreads();
    float m = s_max, lsum = 0.f;
    #pragma unroll
    for (int k = 0; k < 8; ++k) { v[k] = expf(v[k] - m); lsum += v[k]; }
    lsum = waveReduceSum(lsum);
    __syncthreads();
    if (lane == 0) red[wid] = lsum;
    __syncthreads();
    if (tid == 0) { float s = 0.f; for (int i = 0; i < 16; ++i) s += red[i]; s_sum = s; }
    __syncthreads();
    float inv = 1.f / s_sum;
    #pragma unroll
    for (int k = 0; k < 8; ++k) addr_out[tid + k * 1024] = v[k] * inv;
}

// ---------------------------------------------------------------- K5: fused column pass (new_mem + read_vec partials)
// Normal cached accesses: ma/mc should be L3-hits (allocated by K3).
__global__ void k_colpass(const float* __restrict__ ma, const float* __restrict__ mc,
                          const float* __restrict__ addr, const float* __restrict__ cdiff,
                          float* __restrict__ newmem_out, float* __restrict__ rvpart)
{
    int c     = blockIdx.x * 256 + threadIdx.x;   // 0..2559
    int chunk = blockIdx.y;                       // 0..NCHUNK-1
    const int RPC = N_LOC / NCHUNK;               // 64
    int r0 = chunk * RPC, r1 = r0 + RPC;

    float acc = 0.f;
    if (c < A_SIZE) {
        const float* p = ma + c;
        for (int r = r0; r < r1; ++r) {
            float val = p[(size_t)r * A_SIZE];
            float a = addr[r];
            if (r != N_LOC - 1) acc += a * val;
        }
    } else {
        int cc = c - A_SIZE;
        float cd = cdiff[cc];
        const float* p = mc + cc;
        float* o = newmem_out + cc;
        for (int r = r0; r < r1; ++r) {
            float val = p[(size_t)r * C_SIZE];
            float a = addr[r];
            if (r != N_LOC - 1) acc += a * val;
            o[(size_t)r * C_SIZE] = val + a * cd;
        }
    }
    rvpart[(size_t)chunk * D_FULL + c] = acc;
}

// ---------------------------------------------------------------- K6: reduce read_vec partials
__global__ void k_rvreduce(const float* __restrict__ rvpart, float* __restrict__ rv_out)
{
    int c = blockIdx.x * 256 + threadIdx.x;
    if (c >= D_FULL) return;
    float s = 0.f;
    for (int k = 0; k < NCHUNK; ++k) s += rvpart[(size_t)k * D_FULL + c];
    rv_out[c] = s;
}

// ---------------------------------------------------------------- launch
extern "C" void kernel_launch(void* const* d_in, const int* in_sizes, int n_in,
                              void* d_out, int out_size, void* d_ws, size_t ws_size,
                              hipStream_t stream)
{
    const float* h   = (const float*)d_in[0];
    const float* x   = (const float*)d_in[1];
    const float* mc  = (const float*)d_in[2];
    const float* ma  = (const float*)d_in[3];
    const float* ema = (const float*)d_in[4];
    const float* Wq  = (const float*)d_in[5];
    const float* bq  = (const float*)d_in[6];
    const float* us  = (const float*)d_in[7];
    const float* bs  = (const float*)d_in[8];
    const float* ul  = (const float*)d_in[9];
    const float* bl  = (const float*)d_in[10];
    const float* We  = (const float*)d_in[11];
    const float* be  = (const float*)d_in[12];
    const float* Wch = (const float*)d_in[13];
    const float* Wci = (const float*)d_in[14];
    const float* uca = (const float*)d_in[15];
    const float* bca = (const float*)d_in[16];

    float* out = (float*)d_out;
    float* rv_out     = out;                              // 2560
    float* newmem_out = out + D_FULL;                     // 8192*2048
    float* addr_out   = newmem_out + (size_t)N_LOC * C_SIZE; // 8192
    float* newema_out = addr_out + N_LOC;                 // 8192

    float* ws = (float*)d_ws;
    float* w_query = ws;            // 2560
    float* w_erase = ws + 2560;     // 2048
    float* w_wh    = ws + 4608;     // 2048
    float* w_wx    = ws + 6656;     // 2048
    float* w_cdiff = ws + 8704;     // 2048
    float* w_scal  = ws + 10752;    // 8
    float* w_logit = ws + 10760;    // 8192
    float* w_rvp   = ws + 18952;    // NCHUNK*2560

    // K1: all mat-vecs, block-per-row (6656 h-rows + 2048 x-rows), nt W-stream
    k_matvec<<<8704, 256, 0, stream>>>(h, x, Wq, bq, We, be, Wch, Wci,
                                       w_query, w_erase, w_wh, w_wx);
    // K2: scalars + cdiff
    k_scalars<<<1, 1024, 0, stream>>>(h, x, us, bs, ul, bl, uca, bca,
                                      w_query, w_erase, w_wh, w_wx, w_scal, w_cdiff);
    // K3: per-row dot/norm -> logit, new_ema (cached: allocates ma/mc for K5)
    k_rowpass<<<2048, 256, 0, stream>>>(ma, mc, w_query, ema, w_scal, w_logit, newema_out);
    // K4: softmax -> address
    k_softmax<<<1, 1024, 0, stream>>>(w_logit, addr_out);
    // K5: fused new_mem + read_vec partials (cached)
    dim3 g5(D_FULL / 256, NCHUNK);
    k_colpass<<<g5, 256, 0, stream>>>(ma, mc, addr_out, w_cdiff, newmem_out, w_rvp);
    // K6: reduce read_vec partials
    k_rvreduce<<<10, 256, 0, stream>>>(w_rvp, rv_out);
}